// Round 6
// baseline (268.926 us; speedup 1.0000x reference)
//
#include <hip/hip_runtime.h>

#define GIOU_GRID    1024
#define GIOU_THREADS 256
#define UNROLL       4

typedef float v4f __attribute__((ext_vector_type(4)));
typedef int   v4i __attribute__((ext_vector_type(4)));

// CK-style raw buffer-load intrinsic (compiler manages vmcnt for it).
// aux is the cache-policy word: bit0 = SC0. On gfx940+/gfx950, SC0 on a load
// raises the scope past the (CU-scope) L1 -> L1 bypassed, L2/L3 still
// allocate. This is the untested quadrant of the cache-path matrix:
//   plain  = L1 alloc + L2 alloc  -> 1.3-2.6 TB/s (L1 miss-queue serializes, R4)
//   nt     = L1 byp   + L2/L3 byp -> ~3.8 TB/s plateau (R0/R3/R5)
//   sc0    = L1 byp   + L2/L3 alloc -> target: ~131 MB of input is L3-resident
//            across bench iterations (R4: FETCH_SIZE=125MB of 256MB).
__device__ v4f llvm_amdgcn_raw_buffer_load_v4f32(
    v4i rsrc, int voffset, int soffset, int aux) __asm("llvm.amdgcn.raw.buffer.load.v4f32");

__device__ __forceinline__ v4i make_srsrc(const void* p, int bytes) {
    v4i r;
    r.x = (int)(uint32_t)(uintptr_t)p;          // base lo
    r.y = (int)(uint32_t)((uintptr_t)p >> 32);  // base hi, stride=0
    r.z = bytes;                                // num_records in BYTES (stride==0)
    r.w = 0x00020000;                           // raw untyped dword access
    return r;
}

__device__ __forceinline__ float giou_loss(v4f p, v4f t) {
    float area_p = (p.z - p.x) * (p.w - p.y);
    float area_t = (t.z - t.x) * (t.w - t.y);

    float iw = fmaxf(fminf(p.z, t.z) - fmaxf(p.x, t.x), 0.0f);
    float ih = fmaxf(fminf(p.w, t.w) - fmaxf(p.y, t.y), 0.0f);
    float inter = iw * ih;
    float uni   = area_p + area_t - inter;

    float ew = fmaxf(p.z, t.z) - fminf(p.x, t.x);
    float eh = fmaxf(p.w, t.w) - fminf(p.y, t.y);
    float enclose = ew * eh;

    // 1 - giou = 2 - inter/union - union/enclose  (fast rcp: err ~1e-5 << 2.75e-2 threshold)
    return 2.0f - inter * __builtin_amdgcn_rcpf(uni)
                - uni   * __builtin_amdgcn_rcpf(enclose);
}

__global__ __launch_bounds__(GIOU_THREADS) void giou_partial_kernel(
        const v4f* __restrict__ pred,
        const v4f* __restrict__ targ,
        double* __restrict__ partials,
        int n) {
    // balanced contiguous chunk per block: blocks [0,r) get q+1 elems, rest get q
    int b = blockIdx.x;
    int q = n / GIOU_GRID;
    int r = n - q * GIOU_GRID;
    int start = b * q + (b < r ? b : r);
    int end   = start + q + (b < r ? 1 : 0);

    const int T = GIOU_THREADS;

    v4i rp = make_srsrc(pred, n * 16);
    v4i rt = make_srsrc(targ, n * 16);

    float sum = 0.0f;
    int i = start + threadIdx.x;

    // Main loop: 8 sc0 dwordx4 buffer-loads per iteration, contiguous 2x16 KB window.
    for (; i + (UNROLL - 1) * T < end; i += UNROLL * T) {
        v4f p[UNROLL], t[UNROLL];
        #pragma unroll
        for (int u = 0; u < UNROLL; ++u) p[u] = llvm_amdgcn_raw_buffer_load_v4f32(rp, (i + u * T) * 16, 0, 1);
        #pragma unroll
        for (int u = 0; u < UNROLL; ++u) t[u] = llvm_amdgcn_raw_buffer_load_v4f32(rt, (i + u * T) * 16, 0, 1);
        #pragma unroll
        for (int u = 0; u < UNROLL; ++u) sum += giou_loss(p[u], t[u]);
    }
    // 2-wide tail step
    for (; i + T < end; i += 2 * T) {
        v4f p0 = llvm_amdgcn_raw_buffer_load_v4f32(rp, i * 16, 0, 1);
        v4f p1 = llvm_amdgcn_raw_buffer_load_v4f32(rp, (i + T) * 16, 0, 1);
        v4f t0 = llvm_amdgcn_raw_buffer_load_v4f32(rt, i * 16, 0, 1);
        v4f t1 = llvm_amdgcn_raw_buffer_load_v4f32(rt, (i + T) * 16, 0, 1);
        sum += giou_loss(p0, t0);
        sum += giou_loss(p1, t1);
    }
    // final scalar tail
    for (; i < end; i += T)
        sum += giou_loss(llvm_amdgcn_raw_buffer_load_v4f32(rp, i * 16, 0, 1),
                         llvm_amdgcn_raw_buffer_load_v4f32(rt, i * 16, 0, 1));

    // wave-64 butterfly reduction
    #pragma unroll
    for (int off = 32; off > 0; off >>= 1)
        sum += __shfl_down(sum, off, 64);

    __shared__ float wave_sums[GIOU_THREADS / 64];
    int lane = threadIdx.x & 63;
    int wave = threadIdx.x >> 6;
    if (lane == 0) wave_sums[wave] = sum;
    __syncthreads();

    if (threadIdx.x == 0) {
        double bsum = 0.0;
        #pragma unroll
        for (int w = 0; w < GIOU_THREADS / 64; ++w) bsum += (double)wave_sums[w];
        partials[blockIdx.x] = bsum;   // every block writes unconditionally -> no memset needed
    }
}

__global__ __launch_bounds__(GIOU_THREADS) void giou_final_kernel(
        const double* __restrict__ partials,
        float* __restrict__ out,
        int nblocks, int n) {
    double s = 0.0;
    for (int i = threadIdx.x; i < nblocks; i += blockDim.x)
        s += partials[i];

    #pragma unroll
    for (int off = 32; off > 0; off >>= 1)
        s += __shfl_down(s, off, 64);

    __shared__ double wave_sums[GIOU_THREADS / 64];
    int lane = threadIdx.x & 63;
    int wave = threadIdx.x >> 6;
    if (lane == 0) wave_sums[wave] = s;
    __syncthreads();

    if (threadIdx.x == 0) {
        double tot = 0.0;
        #pragma unroll
        for (int w = 0; w < GIOU_THREADS / 64; ++w) tot += wave_sums[w];
        out[0] = (float)(tot / (double)n);
    }
}

extern "C" void kernel_launch(void* const* d_in, const int* in_sizes, int n_in,
                              void* d_out, int out_size, void* d_ws, size_t ws_size,
                              hipStream_t stream) {
    const v4f* pred = (const v4f*)d_in[0];
    const v4f* targ = (const v4f*)d_in[1];
    float* out = (float*)d_out;
    double* partials = (double*)d_ws;   // GIOU_GRID doubles = 8 KB

    int n = in_sizes[0] / 4;            // number of boxes (flat count is n*4)

    giou_partial_kernel<<<GIOU_GRID, GIOU_THREADS, 0, stream>>>(pred, targ, partials, n);
    giou_final_kernel<<<1, GIOU_THREADS, 0, stream>>>(partials, out, GIOU_GRID, n);
}

// Round 7
// 259.406 us; speedup vs baseline: 1.0367x; 1.0367x over previous
//
#include <hip/hip_runtime.h>

#define GIOU_GRID    1024
#define GIOU_THREADS 256
#define UNROLL       4

typedef float v4f __attribute__((ext_vector_type(4)));

__device__ __forceinline__ float giou_loss(v4f p, v4f t) {
    float area_p = (p.z - p.x) * (p.w - p.y);
    float area_t = (t.z - t.x) * (t.w - t.y);

    float iw = fmaxf(fminf(p.z, t.z) - fmaxf(p.x, t.x), 0.0f);
    float ih = fmaxf(fminf(p.w, t.w) - fmaxf(p.y, t.y), 0.0f);
    float inter = iw * ih;
    float uni   = area_p + area_t - inter;

    float ew = fmaxf(p.z, t.z) - fminf(p.x, t.x);
    float eh = fmaxf(p.w, t.w) - fminf(p.y, t.y);
    float enclose = ew * eh;

    // 1 - giou = 2 - inter/union - union/enclose  (fast rcp: err ~1e-5 << 2.75e-2 threshold)
    return 2.0f - inter * __builtin_amdgcn_rcpf(uni)
                - uni   * __builtin_amdgcn_rcpf(enclose);
}

// R7: MIXED-PATH streaming on the R3 base (chunked, UNROLL 4).
// Measured: plain/sc0 path = 2.56 TB/s device (per-CU L1-miss-path cap,
// half served from L3); nt path = 3.8 TB/s (L1+L2/L3 bypass, insensitive to
// MLP/waves/pattern). Theory: the two limiters are PARALLEL resources ->
// split each 8-load batch 5 nt : 3 plain (37.5% ~ optimal 2.56/6.36).
// If superposition holds: max(96MB/2.56, 160MB/3.8) ~ 45 us vs 68 us all-nt.
__global__ __launch_bounds__(GIOU_THREADS) void giou_partial_kernel(
        const v4f* __restrict__ pred,
        const v4f* __restrict__ targ,
        double* __restrict__ partials,
        int n) {
    // balanced contiguous chunk per block: blocks [0,r) get q+1 elems, rest get q
    int b = blockIdx.x;
    int q = n / GIOU_GRID;
    int r = n - q * GIOU_GRID;
    int start = b * q + (b < r ? b : r);
    int end   = start + q + (b < r ? 1 : 0);

    const int T = GIOU_THREADS;

    float sum = 0.0f;
    int i = start + threadIdx.x;

    // Main loop: 5 nt + 3 plain dwordx4 loads per iteration.
    for (; i + (UNROLL - 1) * T < end; i += UNROLL * T) {
        v4f p[UNROLL], t[UNROLL];
        p[0] = __builtin_nontemporal_load(&pred[i + 0 * T]);
        p[1] = __builtin_nontemporal_load(&pred[i + 1 * T]);
        p[2] = __builtin_nontemporal_load(&pred[i + 2 * T]);
        p[3] = pred[i + 3 * T];                       // plain: L1/L2/L3 path
        t[0] = __builtin_nontemporal_load(&targ[i + 0 * T]);
        t[1] = __builtin_nontemporal_load(&targ[i + 1 * T]);
        t[2] = targ[i + 2 * T];                       // plain
        t[3] = targ[i + 3 * T];                       // plain
        #pragma unroll
        for (int u = 0; u < UNROLL; ++u) sum += giou_loss(p[u], t[u]);
    }
    // 2-wide tail step (1 plain of 4)
    for (; i + T < end; i += 2 * T) {
        v4f p0 = __builtin_nontemporal_load(&pred[i]);
        v4f p1 = __builtin_nontemporal_load(&pred[i + T]);
        v4f t0 = __builtin_nontemporal_load(&targ[i]);
        v4f t1 = targ[i + T];
        sum += giou_loss(p0, t0);
        sum += giou_loss(p1, t1);
    }
    // final scalar tail
    for (; i < end; i += T)
        sum += giou_loss(__builtin_nontemporal_load(&pred[i]),
                         __builtin_nontemporal_load(&targ[i]));

    // wave-64 butterfly reduction
    #pragma unroll
    for (int off = 32; off > 0; off >>= 1)
        sum += __shfl_down(sum, off, 64);

    __shared__ float wave_sums[GIOU_THREADS / 64];
    int lane = threadIdx.x & 63;
    int wave = threadIdx.x >> 6;
    if (lane == 0) wave_sums[wave] = sum;
    __syncthreads();

    if (threadIdx.x == 0) {
        double bsum = 0.0;
        #pragma unroll
        for (int w = 0; w < GIOU_THREADS / 64; ++w) bsum += (double)wave_sums[w];
        partials[blockIdx.x] = bsum;   // every block writes unconditionally -> no memset needed
    }
}

__global__ __launch_bounds__(GIOU_THREADS) void giou_final_kernel(
        const double* __restrict__ partials,
        float* __restrict__ out,
        int nblocks, int n) {
    double s = 0.0;
    for (int i = threadIdx.x; i < nblocks; i += blockDim.x)
        s += partials[i];

    #pragma unroll
    for (int off = 32; off > 0; off >>= 1)
        s += __shfl_down(s, off, 64);

    __shared__ double wave_sums[GIOU_THREADS / 64];
    int lane = threadIdx.x & 63;
    int wave = threadIdx.x >> 6;
    if (lane == 0) wave_sums[wave] = s;
    __syncthreads();

    if (threadIdx.x == 0) {
        double tot = 0.0;
        #pragma unroll
        for (int w = 0; w < GIOU_THREADS / 64; ++w) tot += wave_sums[w];
        out[0] = (float)(tot / (double)n);
    }
}

extern "C" void kernel_launch(void* const* d_in, const int* in_sizes, int n_in,
                              void* d_out, int out_size, void* d_ws, size_t ws_size,
                              hipStream_t stream) {
    const v4f* pred = (const v4f*)d_in[0];
    const v4f* targ = (const v4f*)d_in[1];
    float* out = (float*)d_out;
    double* partials = (double*)d_ws;   // GIOU_GRID doubles = 8 KB

    int n = in_sizes[0] / 4;            // number of boxes (flat count is n*4)

    giou_partial_kernel<<<GIOU_GRID, GIOU_THREADS, 0, stream>>>(pred, targ, partials, n);
    giou_final_kernel<<<1, GIOU_THREADS, 0, stream>>>(partials, out, GIOU_GRID, n);
}

// Round 8
// 241.764 us; speedup vs baseline: 1.1123x; 1.0730x over previous
//
#include <hip/hip_runtime.h>

#define GIOU_GRID    1024
#define GIOU_THREADS 256
#define UNROLL       4

typedef float v4f __attribute__((ext_vector_type(4)));

__device__ __forceinline__ float giou_loss(v4f p, v4f t) {
    float area_p = (p.z - p.x) * (p.w - p.y);
    float area_t = (t.z - t.x) * (t.w - t.y);

    float iw = fmaxf(fminf(p.z, t.z) - fmaxf(p.x, t.x), 0.0f);
    float ih = fmaxf(fminf(p.w, t.w) - fmaxf(p.y, t.y), 0.0f);
    float inter = iw * ih;
    float uni   = area_p + area_t - inter;

    float ew = fmaxf(p.z, t.z) - fminf(p.x, t.x);
    float eh = fmaxf(p.w, t.w) - fminf(p.y, t.y);
    float enclose = ew * eh;

    // 1 - giou = 2 - inter/union - union/enclose  (fast rcp: err ~1e-5 << 2.75e-2 threshold)
    return 2.0f - inter * __builtin_amdgcn_rcpf(uni)
                - uni   * __builtin_amdgcn_rcpf(enclose);
}

// FINAL (R3 restored — best verified: 239.6 us). Session findings:
//  - nt loads are load-bearing: plain/sc0 path caps at 2.56 TB/s device
//    (L1 miss-path serialization; R4/R6: 100 us, FETCH=125MB, half L3-served).
//  - nt path plateaus at ~3.8 TB/s, INSENSITIVE to wave count (R1), MLP
//    (R2 UNROLL8, R5 explicit A/B pipeline), access pattern (R3 chunked),
//    and path-mixing hurts (R7: plain loads throttle the wave's vmcnt drain).
//  - Remaining dur_us window is harness re-poison fills (2x74us) + launch
//    overhead; kernel is at its achievable streaming floor.
__global__ __launch_bounds__(GIOU_THREADS) void giou_partial_kernel(
        const v4f* __restrict__ pred,
        const v4f* __restrict__ targ,
        double* __restrict__ partials,
        int n) {
    // balanced chunk split: blocks [0,r) get q+1 elems, rest get q
    int b = blockIdx.x;
    int q = n / GIOU_GRID;
    int r = n - q * GIOU_GRID;
    int start = b * q + (b < r ? b : r);
    int end   = start + q + (b < r ? 1 : 0);

    float sum = 0.0f;
    int i = start + threadIdx.x;

    // Main loop: 8 nontemporal dwordx4 loads per iteration, contiguous window.
    for (; i + (UNROLL - 1) * GIOU_THREADS < end; i += UNROLL * GIOU_THREADS) {
        v4f p[UNROLL], t[UNROLL];
        #pragma unroll
        for (int u = 0; u < UNROLL; ++u) p[u] = __builtin_nontemporal_load(&pred[i + u * GIOU_THREADS]);
        #pragma unroll
        for (int u = 0; u < UNROLL; ++u) t[u] = __builtin_nontemporal_load(&targ[i + u * GIOU_THREADS]);
        #pragma unroll
        for (int u = 0; u < UNROLL; ++u) sum += giou_loss(p[u], t[u]);
    }
    // 2-wide tail step
    for (; i + GIOU_THREADS < end; i += 2 * GIOU_THREADS) {
        v4f p0 = __builtin_nontemporal_load(&pred[i]);
        v4f p1 = __builtin_nontemporal_load(&pred[i + GIOU_THREADS]);
        v4f t0 = __builtin_nontemporal_load(&targ[i]);
        v4f t1 = __builtin_nontemporal_load(&targ[i + GIOU_THREADS]);
        sum += giou_loss(p0, t0);
        sum += giou_loss(p1, t1);
    }
    // final scalar tail
    for (; i < end; i += GIOU_THREADS)
        sum += giou_loss(__builtin_nontemporal_load(&pred[i]),
                         __builtin_nontemporal_load(&targ[i]));

    // wave-64 butterfly reduction
    #pragma unroll
    for (int off = 32; off > 0; off >>= 1)
        sum += __shfl_down(sum, off, 64);

    __shared__ float wave_sums[GIOU_THREADS / 64];
    int lane = threadIdx.x & 63;
    int wave = threadIdx.x >> 6;
    if (lane == 0) wave_sums[wave] = sum;
    __syncthreads();

    if (threadIdx.x == 0) {
        double bsum = 0.0;
        #pragma unroll
        for (int w = 0; w < GIOU_THREADS / 64; ++w) bsum += (double)wave_sums[w];
        partials[blockIdx.x] = bsum;   // every block writes unconditionally -> no memset needed
    }
}

__global__ __launch_bounds__(GIOU_THREADS) void giou_final_kernel(
        const double* __restrict__ partials,
        float* __restrict__ out,
        int nblocks, int n) {
    double s = 0.0;
    for (int i = threadIdx.x; i < nblocks; i += blockDim.x)
        s += partials[i];

    #pragma unroll
    for (int off = 32; off > 0; off >>= 1)
        s += __shfl_down(s, off, 64);

    __shared__ double wave_sums[GIOU_THREADS / 64];
    int lane = threadIdx.x & 63;
    int wave = threadIdx.x >> 6;
    if (lane == 0) wave_sums[wave] = s;
    __syncthreads();

    if (threadIdx.x == 0) {
        double tot = 0.0;
        #pragma unroll
        for (int w = 0; w < GIOU_THREADS / 64; ++w) tot += wave_sums[w];
        out[0] = (float)(tot / (double)n);
    }
}

extern "C" void kernel_launch(void* const* d_in, const int* in_sizes, int n_in,
                              void* d_out, int out_size, void* d_ws, size_t ws_size,
                              hipStream_t stream) {
    const v4f* pred = (const v4f*)d_in[0];
    const v4f* targ = (const v4f*)d_in[1];
    float* out = (float*)d_out;
    double* partials = (double*)d_ws;   // GIOU_GRID doubles = 8 KB

    int n = in_sizes[0] / 4;            // number of boxes (flat count is n*4)

    giou_partial_kernel<<<GIOU_GRID, GIOU_THREADS, 0, stream>>>(pred, targ, partials, n);
    giou_final_kernel<<<1, GIOU_THREADS, 0, stream>>>(partials, out, GIOU_GRID, n);
}